// Round 2
// baseline (159.957 us; speedup 1.0000x reference)
//
#include <hip/hip_runtime.h>
#include <hip/hip_bf16.h>
#include <math.h>

// Problem constants
#define B_SZ   1024
#define F_SZ   1024
#define NKER   100
#define DKER   5
#define CCOLS  (NKER * DKER)   // 500
#define OUTW   (F_SZ + NKER)   // 1124

#if defined(__has_builtin)
#if __has_builtin(__builtin_amdgcn_exp2f)
#define EXP2F(x) __builtin_amdgcn_exp2f(x)
#else
#define EXP2F(x) exp2f(x)
#endif
#else
#define EXP2F(x) exp2f(x)
#endif

// ---------------------------------------------------------------------------
// Kernel 1: copy x into out[:, :1024] and zero the feat region out[:, 1024:]
// One block per row; 320 threads: t<256 copy a float4 of x, t in [256,281)
// zero a float4 of the feat region. Row stride 1124 floats is 4-aligned.
// ---------------------------------------------------------------------------
__global__ __launch_bounds__(320) void init_kernel(const float* __restrict__ x,
                                                   float* __restrict__ out) {
    const int row = blockIdx.x;
    const int t = threadIdx.x;
    if (t < 256) {
        const float4 v = *reinterpret_cast<const float4*>(&x[row * F_SZ + t * 4]);
        *reinterpret_cast<float4*>(&out[row * OUTW + t * 4]) = v;
    } else if (t < 256 + 25) {
        float4 z = make_float4(0.f, 0.f, 0.f, 0.f);
        *reinterpret_cast<float4*>(&out[row * OUTW + F_SZ + (t - 256) * 4]) = z;
    }
}

// ---------------------------------------------------------------------------
// Kernel 2: mt[c][j] = log2(e) * sum_f x[j][f] * T[f][c]   (c < 500, j < 1024)
// Tiled fp32 GEMM (no fp32 MFMA on CDNA4 -> vector ALU). BM=32 (c), BN=64 (j),
// BK=16 (f). 256 threads, each computes 2 c x 4 j outputs. Grid = 16 x 16.
// ---------------------------------------------------------------------------
#define BMC 32
#define BNJ 64
#define BKF 16

__global__ __launch_bounds__(256) void gemm_kernel(const float* __restrict__ x,
                                                   const float* __restrict__ T,
                                                   float* __restrict__ mt) {
    __shared__ float Ts[BKF][BMC];        // [f][c]
    __shared__ float Xs[BKF][BNJ + 4];    // [f][j], pad 4 floats (16B) keeps b128 align
    const int tid = threadIdx.x;
    const int c0 = blockIdx.x * BMC;
    const int j0 = blockIdx.y * BNJ;
    const int tcx = tid >> 4;    // 0..15 -> c sub-tile
    const int tjx = tid & 15;    // 0..15 -> j sub-tile

    float acc[2][4];
    #pragma unroll
    for (int a = 0; a < 2; ++a)
        #pragma unroll
        for (int b = 0; b < 4; ++b) acc[a][b] = 0.f;

    for (int f0 = 0; f0 < F_SZ; f0 += BKF) {
        // --- load T tile: 16 x 32 floats, threads 0..127, one float4 each
        if (tid < 128) {
            const int r = tid >> 3;          // 0..15 (f)
            const int cc = (tid & 7) * 4;    // 0..28 (c)
            const int c = c0 + cc;
            float4 v;
            if (c + 3 < CCOLS) {
                v = *reinterpret_cast<const float4*>(&T[(f0 + r) * CCOLS + c]);
            } else {
                v.x = (c + 0 < CCOLS) ? T[(f0 + r) * CCOLS + c + 0] : 0.f;
                v.y = (c + 1 < CCOLS) ? T[(f0 + r) * CCOLS + c + 1] : 0.f;
                v.z = (c + 2 < CCOLS) ? T[(f0 + r) * CCOLS + c + 2] : 0.f;
                v.w = (c + 3 < CCOLS) ? T[(f0 + r) * CCOLS + c + 3] : 0.f;
            }
            *reinterpret_cast<float4*>(&Ts[r][cc]) = v;
        }
        // --- load x tile transposed: 64 j x 16 f; each thread one float4 of x
        {
            const int jr = tid >> 2;          // 0..63
            const int fc = (tid & 3) * 4;     // 0,4,8,12
            const float4 v =
                *reinterpret_cast<const float4*>(&x[(j0 + jr) * F_SZ + f0 + fc]);
            Xs[fc + 0][jr] = v.x;
            Xs[fc + 1][jr] = v.y;
            Xs[fc + 2][jr] = v.z;
            Xs[fc + 3][jr] = v.w;
        }
        __syncthreads();

        #pragma unroll
        for (int kk = 0; kk < BKF; ++kk) {
            const float a0 = Ts[kk][tcx * 2 + 0];
            const float a1 = Ts[kk][tcx * 2 + 1];
            const float4 b = *reinterpret_cast<const float4*>(&Xs[kk][tjx * 4]);
            acc[0][0] += a0 * b.x;
            acc[0][1] += a0 * b.y;
            acc[0][2] += a0 * b.z;
            acc[0][3] += a0 * b.w;
            acc[1][0] += a1 * b.x;
            acc[1][1] += a1 * b.y;
            acc[1][2] += a1 * b.z;
            acc[1][3] += a1 * b.w;
        }
        __syncthreads();
    }

    const float LOG2E = 1.44269504088896340736f;
    #pragma unroll
    for (int cc = 0; cc < 2; ++cc) {
        const int c = c0 + tcx * 2 + cc;
        if (c < CCOLS) {
            const int j = j0 + tjx * 4;
            float4 o;
            o.x = acc[cc][0] * LOG2E;
            o.y = acc[cc][1] * LOG2E;
            o.z = acc[cc][2] * LOG2E;
            o.w = acc[cc][3] * LOG2E;
            *reinterpret_cast<float4*>(&mt[c * B_SZ + j]) = o;
        }
    }
}

// ---------------------------------------------------------------------------
// Kernel 3: feat[i,k] += sum_{j in chunk} exp2(-sum_d |mt[k*5+d][i]-mt[k*5+d][j]|)
// grid = (JSPLIT=2, B/256=4, K=100); block 256 threads, one i per thread.
// j-chunk of 512 staged in LDS rows of 8 floats (b128+b32 broadcast reads:
// j is wave-uniform in the inner loop -> same-address broadcast, conflict-free).
// mt is pre-scaled by log2(e), so exp2 gives exp(-l1) directly.
// ---------------------------------------------------------------------------
#define JCHUNK 512

__global__ __launch_bounds__(256) void pair_kernel(const float* __restrict__ mt,
                                                   float* __restrict__ out) {
    __shared__ float mj[JCHUNK][8];
    const int tid = threadIdx.x;
    const int j0 = blockIdx.x * JCHUNK;
    const int i = blockIdx.y * 256 + tid;
    const int k = blockIdx.z;
    const int cbase = k * DKER;

    // stage the j-chunk: 5 rows x 512 coalesced global loads
    #pragma unroll
    for (int d = 0; d < DKER; ++d) {
        #pragma unroll
        for (int rep = 0; rep < JCHUNK / 256; ++rep) {
            const int jr = rep * 256 + tid;
            mj[jr][d] = mt[(cbase + d) * B_SZ + j0 + jr];
        }
    }
    // this thread's own point (coalesced: consecutive i across lanes)
    const float m0 = mt[(cbase + 0) * B_SZ + i];
    const float m1 = mt[(cbase + 1) * B_SZ + i];
    const float m2 = mt[(cbase + 2) * B_SZ + i];
    const float m3 = mt[(cbase + 3) * B_SZ + i];
    const float m4 = mt[(cbase + 4) * B_SZ + i];
    __syncthreads();

    float acc = 0.f;
    #pragma unroll 4
    for (int j = 0; j < JCHUNK; ++j) {
        const float4 v = *reinterpret_cast<const float4*>(&mj[j][0]);
        const float v4 = mj[j][4];
        const float l = fabsf(m0 - v.x) + fabsf(m1 - v.y) + fabsf(m2 - v.z) +
                        fabsf(m3 - v.w) + fabsf(m4 - v4);
        acc += EXP2F(-l);
    }
    atomicAdd(&out[i * OUTW + F_SZ + k], acc);
}

// ---------------------------------------------------------------------------
extern "C" void kernel_launch(void* const* d_in, const int* in_sizes, int n_in,
                              void* d_out, int out_size, void* d_ws, size_t ws_size,
                              hipStream_t stream) {
    const float* x = (const float*)d_in[0];   // [1024, 1024]
    const float* T = (const float*)d_in[1];   // [1024, 500]
    float* out = (float*)d_out;               // [1024, 1124]
    float* mt = (float*)d_ws;                 // [500][1024] fp32 = 2 MB

    // 1) copy x + zero feat region (harness poisons d_out)
    init_kernel<<<dim3(B_SZ), 320, 0, stream>>>(x, out);
    // 2) mt[c][j] = log2e * (x @ T)^T
    gemm_kernel<<<dim3((CCOLS + BMC - 1) / BMC, B_SZ / BNJ), 256, 0, stream>>>(x, T, mt);
    // 3) pairwise exp-L1 accumulation into out[:, 1024:]
    pair_kernel<<<dim3(B_SZ / JCHUNK, B_SZ / 256, NKER), 256, 0, stream>>>(mt, out);
}